// Round 5
// baseline (117.019 us; speedup 1.0000x reference)
//
#include <hip/hip_runtime.h>
#include <hip/hip_fp16.h>

// grid : (B=4, gh=16, gw=16, gd=8, nc=12)  fp32
// guide: (B=4, H=1024, W=1024)             fp32
// inp  : (B=4, H=1024, W=1024, 3)          fp32
// out  : (B=4, H=1024, W=1024, 3)          fp32
//
// Block = 64x64 pixel tile (256 thr, 16 rows/thread). Rows 0..31 use y-cell
// pair (ty-1,ty); rows 32..63 use (ty,ty+1)  [clamped].
// Stage 1 (fp16 LDS, 40 KB):
//   region A: [slot:3][z:8][x:64] -> 4x half2, channels 0..7   (24 KB)
//             slot 0/1/2 = clamp(ty-1)/ty/clamp(ty+1)
//   region B: [v:2][z:8][x:64]   -> {ycLo:(c8,c9),(c10,c11), ycHi:same} (16 KB)
//             v = row>=32 variant (pair ycLo,ycHi)
// Stage 2: per row, 6 conflict-free ds_read_b128, y/z lerp + affine in
// packed fp16, f32 store. Streamed guide/inp prefetched in two 8-row halves
// (second half issued just after __syncthreads to dodge the vmcnt(0) drain).

struct __align__(16) H2x4 { __half2 x, y, z, w; };

__global__ __launch_bounds__(256, 4) void BilateralSliceApply_kernel(
    const float* __restrict__ grid,
    const float* __restrict__ guide,
    const float* __restrict__ inp,
    float* __restrict__ out)
{
    __shared__ H2x4 lA[24 * 64];  // (slot*8+z)*64 + x   24 KB
    __shared__ H2x4 lB[16 * 64];  // (v*8+z)*64 + x      16 KB

    const int tx = blockIdx.x;    // 0..15
    const int ty = blockIdx.y;    // 0..15
    const int b  = blockIdx.z;    // 0..3
    const int t  = threadIdx.x;   // 0..255
    const int xl = t & 63;
    const int r0 = t >> 6;        // 0..3 ; rows r0+4k, k=0..15

    const int x0 = tx << 6;
    const int y0 = ty << 6;

    const int s0 = ty > 0 ? ty - 1 : 0;
    const int s1 = ty;
    const int s2 = ty < 15 ? ty + 1 : 15;

    // ---- prefetch first half (rows r0+4k, k=0..7) ----
    const int pp0 = (((b << 10) + y0 + r0) << 10) + x0 + xl;
    float  gzA[8];
    float3 inA[8];
#pragma unroll
    for (int k = 0; k < 8; ++k) {
        const int pp = pp0 + (k << 12);
        gzA[k] = guide[pp];
        inA[k] = *(const float3*)(inp + (size_t)pp * 3);
    }

    // ---------------- stage 1: x-interp -> fp16 LDS ----------------
    const int fx  = (xl < 32) ? (tx - 1) : tx;
    const int ix0 = fx < 0 ? 0 : fx;
    const int ix1 = (fx + 1 > 15) ? 15 : fx + 1;
    const float wx1 = ((float)(x0 + xl) + 0.5f) * 0.015625f - 0.5f - (float)fx;
    const int bbase = b << 4;

    for (int L = r0; L < 40; L += 4) {   // wave-uniform L each iter
        const int z = L & 7;
        const int w = L >> 3;            // 0,1,2 -> region A ; 3,4 -> region B
        if (w < 3) {
            const int ycell = (w == 0) ? s0 : (w == 1 ? s1 : s2);
            const int cb = (bbase + ycell) << 4;
            const float* p0 = grid + (size_t)(((cb + ix0) << 3) + z) * 12;
            const float* p1 = grid + (size_t)(((cb + ix1) << 3) + z) * 12;
            const float4 a0 = *(const float4*)(p0 + 0);
            const float4 a1 = *(const float4*)(p0 + 4);
            const float4 b0 = *(const float4*)(p1 + 0);
            const float4 b1 = *(const float4*)(p1 + 4);
            H2x4 r;
            r.x = __floats2half2_rn(fmaf(wx1, b0.x - a0.x, a0.x),
                                    fmaf(wx1, b0.y - a0.y, a0.y));
            r.y = __floats2half2_rn(fmaf(wx1, b0.z - a0.z, a0.z),
                                    fmaf(wx1, b0.w - a0.w, a0.w));
            r.z = __floats2half2_rn(fmaf(wx1, b1.x - a1.x, a1.x),
                                    fmaf(wx1, b1.y - a1.y, a1.y));
            r.w = __floats2half2_rn(fmaf(wx1, b1.z - a1.z, a1.z),
                                    fmaf(wx1, b1.w - a1.w, a1.w));
            lA[(L << 6) + xl] = r;
        } else {
            const int v  = w - 3;
            const int pA = v ? s1 : s0;
            const int pB = v ? s2 : s1;
            const int cbA = (bbase + pA) << 4;
            const int cbB = (bbase + pB) << 4;
            const float4 a0 = *(const float4*)(grid + (size_t)(((cbA + ix0) << 3) + z) * 12 + 8);
            const float4 a1 = *(const float4*)(grid + (size_t)(((cbA + ix1) << 3) + z) * 12 + 8);
            const float4 b0 = *(const float4*)(grid + (size_t)(((cbB + ix0) << 3) + z) * 12 + 8);
            const float4 b1 = *(const float4*)(grid + (size_t)(((cbB + ix1) << 3) + z) * 12 + 8);
            H2x4 r;
            r.x = __floats2half2_rn(fmaf(wx1, a1.x - a0.x, a0.x),
                                    fmaf(wx1, a1.y - a0.y, a0.y));
            r.y = __floats2half2_rn(fmaf(wx1, a1.z - a0.z, a0.z),
                                    fmaf(wx1, a1.w - a0.w, a0.w));
            r.z = __floats2half2_rn(fmaf(wx1, b1.x - b0.x, b0.x),
                                    fmaf(wx1, b1.y - b0.y, b0.y));
            r.w = __floats2half2_rn(fmaf(wx1, b1.z - b0.z, b0.z),
                                    fmaf(wx1, b1.w - b0.w, b0.w));
            lB[((L - 24) << 6) + xl] = r;
        }
    }
    __syncthreads();

    // ---- prefetch second half NOW (stays in flight under first-half compute) ----
    float  gzB[8];
    float3 inB[8];
#pragma unroll
    for (int k = 0; k < 8; ++k) {
        const int pp = pp0 + ((k + 8) << 12);
        gzB[k] = guide[pp];
        inB[k] = *(const float3*)(inp + (size_t)pp * 3);
    }

    // ---------------- stage 2: y/z lerp + affine (packed fp16) ----------------
#pragma unroll
    for (int k = 0; k < 16; ++k) {
        const int v   = k >> 3;            // 0: rows<32, 1: rows>=32
        const int row = r0 + (k << 2);
        const int pp  = pp0 + (k << 12);

        // wy1 = (row+0.5)/64 + 0.5 - v
        const float wy1 = ((float)row + 0.5f) * 0.015625f + (v ? -0.5f : 0.5f);
        const float wy0 = 1.0f - wy1;

        const float gz  = (v ? gzB[k - 8] : gzA[k]) * 8.0f;
        const float fz  = floorf(gz - 0.5f);
        const float wz1 = gz - 0.5f - fz;
        const float wz0 = 1.0f - wz1;
        const int ifz = (int)fz;
        const int iz0 = ifz < 0 ? 0 : (ifz > 7 ? 7 : ifz);
        const int nz  = ifz + 1;
        const int iz1 = nz < 0 ? 0 : (nz > 7 ? 7 : nz);

        const __half2 hA0 = __float2half2_rn(wy0 * wz0);
        const __half2 hA1 = __float2half2_rn(wy0 * wz1);
        const __half2 hB0 = __float2half2_rn(wy1 * wz0);
        const __half2 hB1 = __float2half2_rn(wy1 * wz1);

        const int slotLo = v;        // lower y-cell slot
        const int slotHi = v + 1;

        const H2x4 vA00 = lA[(((slotLo << 3) + iz0) << 6) + xl];
        const H2x4 vA01 = lA[(((slotLo << 3) + iz1) << 6) + xl];
        const H2x4 vA10 = lA[(((slotHi << 3) + iz0) << 6) + xl];
        const H2x4 vA11 = lA[(((slotHi << 3) + iz1) << 6) + xl];
        const H2x4 vB0  = lB[(((v << 3) + iz0) << 6) + xl];
        const H2x4 vB1  = lB[(((v << 3) + iz1) << 6) + xl];

        __half2 q0 = __hmul2(hA0, vA00.x);             // (c0,c1)
        __half2 q1 = __hmul2(hA0, vA00.y);             // (c2,c3)
        __half2 q2 = __hmul2(hA0, vA00.z);             // (c4,c5)
        __half2 q3 = __hmul2(hA0, vA00.w);             // (c6,c7)
        q0 = __hfma2(hA1, vA01.x, q0);
        q1 = __hfma2(hA1, vA01.y, q1);
        q2 = __hfma2(hA1, vA01.z, q2);
        q3 = __hfma2(hA1, vA01.w, q3);
        q0 = __hfma2(hB0, vA10.x, q0);
        q1 = __hfma2(hB0, vA10.y, q1);
        q2 = __hfma2(hB0, vA10.z, q2);
        q3 = __hfma2(hB0, vA10.w, q3);
        q0 = __hfma2(hB1, vA11.x, q0);
        q1 = __hfma2(hB1, vA11.y, q1);
        q2 = __hfma2(hB1, vA11.z, q2);
        q3 = __hfma2(hB1, vA11.w, q3);

        __half2 q4 = __hmul2(hA0, vB0.x);              // (c8,c9)
        __half2 q5 = __hmul2(hA0, vB0.y);              // (c10,c11)
        q4 = __hfma2(hA1, vB1.x, q4);
        q5 = __hfma2(hA1, vB1.y, q5);
        q4 = __hfma2(hB0, vB0.z, q4);
        q5 = __hfma2(hB0, vB0.w, q5);
        q4 = __hfma2(hB1, vB1.z, q4);
        q5 = __hfma2(hB1, vB1.w, q5);

        const float3 in = v ? inB[k - 8] : inA[k];
        const __half2 i01 = __floats2half2_rn(in.x, in.y);
        const __half2 i21 = __floats2half2_rn(in.z, 1.0f);

        __half2 r0h = __hmul2(q0, i01); r0h = __hfma2(q1, i21, r0h);
        __half2 r1h = __hmul2(q2, i01); r1h = __hfma2(q3, i21, r1h);
        __half2 r2h = __hmul2(q4, i01); r2h = __hfma2(q5, i21, r2h);

        float3 o;
        o.x = __low2float(r0h) + __high2float(r0h);
        o.y = __low2float(r1h) + __high2float(r1h);
        o.z = __low2float(r2h) + __high2float(r2h);
        *(float3*)(out + (size_t)pp * 3) = o;
    }
}

extern "C" void kernel_launch(void* const* d_in, const int* in_sizes, int n_in,
                              void* d_out, int out_size, void* d_ws, size_t ws_size,
                              hipStream_t stream) {
    const float* grid  = (const float*)d_in[0];
    const float* guide = (const float*)d_in[1];
    const float* inp   = (const float*)d_in[2];
    float* out = (float*)d_out;

    dim3 gridDim(16, 16, 4);   // 64x64 tiles, batch
    BilateralSliceApply_kernel<<<gridDim, 256, 0, stream>>>(grid, guide, inp, out);
}